// Round 1
// baseline (511.661 us; speedup 1.0000x reference)
//
#include <hip/hip_runtime.h>

// x: (T=128, B=4, E=10000, F=16) fp32, dummy_index d = 0.
// out: (128, 4, 10000, 15) fp32 = tanh(cumsum_T(x[...,1:] * dt)),
// dt[0] = t0+t1, dt[k] = t[k]-t[k-1], t = x[...,0].
//
// Mapping: 4 threads per (b,e) group; each thread loads one float4 per
// timestep (fully coalesced, 1 KB/wave-load). dt channel (lane 4k's .x)
// broadcast to the quad via DPP quad_perm (1 VALU op, no LDS).
//
// Store fix (this round): instead of 4 scalar stores/thread at 60B lane
// stride (~240 line-transactions per wave-iteration for a 15-line
// footprint), results are staged in a per-wave 240-float LDS strip and
// written back as 60 contiguous float4 lanes -> 15 line-transactions.
// Wave-internal exchange only: no __syncthreads, just lgkmcnt(0).

#define TT   128
#define X4_T 160000            // per-t stride in float4 units (B*E*F/4)
#define O_T4 150000            // per-t stride in float4 units for out (B*E*15/4)

__device__ __forceinline__ float fast_tanh(float x) {
  // tanh(x) = 1 - 2/(exp(2x)+1); saturates correctly at +/-inf.
  float e = __expf(2.0f * x);
  return 1.0f - __fdividef(2.0f, e + 1.0f);
}

// Broadcast lane (4k).x to lanes 4k..4k+3: DPP quad_perm[0,0,0,0] = ctrl 0.
__device__ __forceinline__ float quad_bcast0(float v) {
  return __int_as_float(
      __builtin_amdgcn_mov_dpp(__float_as_int(v), 0, 0xf, 0xf, true));
}

__global__ __launch_bounds__(256) void integ_kernel(const float* __restrict__ x,
                                                    float* __restrict__ out) {
  // Per-wave staging strip: 16 groups * 15 floats = 240 floats = 960 B.
  // 960 % 16 == 0 so each wave's strip is float4-aligned.
  __shared__ __align__(16) float stage[4][240];

  const int tid  = threadIdx.x;
  const int gid  = blockIdx.x * 256 + tid;   // grid exact: 625*256 = 160000
  const int idx  = gid >> 2;                 // (b,e) group index, 0..39999
  const int sub  = gid & 3;                  // which float4 within F=16
  const int wid  = tid >> 6;                 // wave in block, 0..3
  const int lane = tid & 63;
  const int g    = lane >> 2;                // group within wave, 0..15

  const float4* xv = reinterpret_cast<const float4*>(x) + ((size_t)idx * 4 + sub);

  // LDS write base: feature jo = 4*sub - 1 + c (c = 1..3 always, c = 0 iff sub>0).
  float* lw = &stage[wid][0] + (g * 15 + 4 * sub - 1);
  // Coalesced store lane: lanes 0..59 each own one float4 of the 240-float strip.
  const float4* ls = reinterpret_cast<const float4*>(&stage[wid][0]) + lane;
  const int gbase = blockIdx.x * 64 + wid * 16;   // first group of this wave
  float4* op = reinterpret_cast<float4*>(out + (size_t)gbase * 15) + lane;

  // --- t = 0: dt = t[0] + t[1] (peek at t=1) ---
  float4 v   = xv[0];
  float4 vn1 = xv[(size_t)X4_T];
  float4 vn2 = xv[(size_t)2 * X4_T];

  float t0 = quad_bcast0(v.x);
  float t1 = quad_bcast0(vn1.x);
  float dt = t0 + t1;
  float a0 = v.x * dt;
  float a1 = v.y * dt;
  float a2 = v.z * dt;
  float a3 = v.w * dt;

  if (sub) lw[0] = fast_tanh(a0);
  lw[1] = fast_tanh(a1);
  lw[2] = fast_tanh(a2);
  lw[3] = fast_tanh(a3);
  asm volatile("s_waitcnt lgkmcnt(0)" ::: "memory");
  if (lane < 60) op[0] = *ls;

  float tprev = t0;
  v = vn1;
  vn1 = vn2;

  // --- t = 1..127: dt = t[k] - t[k-1] ---
#pragma unroll 4
  for (int t = 1; t < TT; ++t) {
    // Prefetch t+2 (clamped; redundant tail reload is L2-hot and harmless).
    int tn = (t + 2 < TT) ? t + 2 : TT - 1;
    vn2 = xv[(size_t)tn * X4_T];

    float tc = quad_bcast0(v.x);
    dt = tc - tprev;
    a0 = fmaf(v.x, dt, a0);
    a1 = fmaf(v.y, dt, a1);
    a2 = fmaf(v.z, dt, a2);
    a3 = fmaf(v.w, dt, a3);

    if (sub) lw[0] = fast_tanh(a0);
    lw[1] = fast_tanh(a1);
    lw[2] = fast_tanh(a2);
    lw[3] = fast_tanh(a3);
    // Wave-internal LDS exchange: DS pipe is in-order per wave, so the next
    // iteration's ds_writes cannot pass this iteration's ds_read.
    asm volatile("s_waitcnt lgkmcnt(0)" ::: "memory");
    if (lane < 60) op[(size_t)t * O_T4] = *ls;

    tprev = tc;
    v = vn1;
    vn1 = vn2;
  }
}

extern "C" void kernel_launch(void* const* d_in, const int* in_sizes, int n_in,
                              void* d_out, int out_size, void* d_ws, size_t ws_size,
                              hipStream_t stream) {
  const float* x = (const float*)d_in[0];
  float* out = (float*)d_out;
  // 40000 groups * 4 threads = 160000 threads = 625 blocks of 256 exactly.
  integ_kernel<<<dim3(625), dim3(256), 0, stream>>>(x, out);
}